// Round 1
// baseline (548.097 us; speedup 1.0000x reference)
//
#include <hip/hip_runtime.h>
#include <math.h>

typedef int    intx8    __attribute__((ext_vector_type(8)));   // 8 dwords = 32 fp8
typedef float  floatx16 __attribute__((ext_vector_type(16)));  // MFMA 32x32 C/D

#define N_ROWS 8192
#define H_DIM  1024
#define V_DIM  32000
#define V_PAD  32768         // padded V: pad cols killed via bias = -1e30
#define IGNORE_INDEX (-100)

#define S_SPLITS 16          // 16 splits x 16 tiles x 128 cols = 32768
#define TILES_PER_SPLIT 16
#define BM 256
#define BN 128
#define BK 64                // 4 k-units of 16B; one K=64 MFMA step
#define KSTEPS 16            // H_DIM / BK
#define TOTAL_STEPS (TILES_PER_SPLIT * KSTEPS)   // 256

#define LOG2E 1.4426950408889634f
#define LN2   0.6931471805599453f

// fp32 [R][1024] row-major -> fp8 e4m3 (value*scale), "unit-transposed"
// [64 k-units][Rstride][16B]. One thread per (u, r): 64B contiguous read, 16B coalesced write.
__global__ __launch_bounds__(256) void convert_fp8(const float* __restrict__ in,
                                                   unsigned char* __restrict__ out,
                                                   int Rstride, float scale) {
  const int r = blockIdx.x * 256 + threadIdx.x;
  const int u = blockIdx.y;                  // k-unit 0..63
  const float4* src = (const float4*)(in + (size_t)r * H_DIM + u * 16);
  uint4 res;
#pragma unroll
  for (int j = 0; j < 4; ++j) {
    const float4 v = src[j];
    int p = __builtin_amdgcn_cvt_pk_fp8_f32(v.x * scale, v.y * scale, 0, false);
    p = __builtin_amdgcn_cvt_pk_fp8_f32(v.z * scale, v.w * scale, p, true);
    ((int*)&res)[j] = p;
  }
  *(uint4*)(out + ((size_t)u * Rstride + r) * 16) = res;
}

// Padded bias, pre-scaled to base-2 domain. Pad cols get -1e30 -> exp2 -> 0
// (poisoned pad weights give finite acc; -1e30 dominates).
__global__ __launch_bounds__(256) void pad_bias(const float* __restrict__ bias,
                                                float* __restrict__ biasp) {
  const int i = blockIdx.x * 256 + threadIdx.x;
  biasp[i] = (i < V_DIM) ? bias[i] * LOG2E : -1e30f;
}

// Fused GEMM + sumexp. fp8 e4m3, x pre-scaled by log2e (base-2 softmax domain).
// mfma_scale_f32_32x32x64_f8f6f4, unity scales (0x7F = E8M0 2^0).
//
// Pipelined schedule (T3+T4+T5): BK=64, LDS double-buffered (2x24KB) with
// counted s_waitcnt vmcnt(6) -- loads for step k+1 stay in flight across raw
// s_barrier()s; the vmcnt(0)-before-barrier drain of the old 2-phase loop is
// gone. Bias slice lives in LDS (8KB, loaded once in the prologue) so NO other
// vmem op perturbs the in-order vmcnt counting inside the main loop.
// Per wave per step: 12 ds_read_b128 + 8 MFMA; accumulation order per lane is
// identical to the BK=128 version (units (0,1),(4,5),... per half) -> bitwise
// identical results.
// Grid 32x16 = 512 blocks = exactly 2/CU (56KB LDS x2 = 112KB/CU): one clean
// residency round, no tail.

#define STAGE(ST, CUR) do {                                                              \
    const int _ss = (ST);                                                                \
    const int _ks = _ss & 15;                                                            \
    const int _ct = _ss >> 4;                                                            \
    const int _ub = _ks * 4;                                                             \
    const int _n0 = (sidx * TILES_PER_SPLIT + _ct) * BN;                                 \
    _Pragma("unroll")                                                                    \
    for (int _j = 0; _j < 4; ++_j) {                                                     \
      const int _c = _j * 4 + w, _u = _c >> 2, _rb = _c & 3;                             \
      __builtin_amdgcn_global_load_lds(                                                  \
          (const __attribute__((address_space(1))) void*)(xs +                           \
              ((size_t)(_ub + _u) * N_ROWS + row0 + _rb * 64 + lane) * 16),              \
          (__attribute__((address_space(3))) void*)(smA + (CUR) * (4 * 256 * 16) +       \
              (_u * 256 + _rb * 64 + lane) * 16),                                        \
          16, 0, 0);                                                                     \
    }                                                                                    \
    _Pragma("unroll")                                                                    \
    for (int _j = 0; _j < 2; ++_j) {                                                     \
      const int _c = _j * 4 + w, _u = _c >> 1, _rb = _c & 1;                             \
      __builtin_amdgcn_global_load_lds(                                                  \
          (const __attribute__((address_space(1))) void*)(wsb +                          \
              ((size_t)(_ub + _u) * V_PAD + _n0 + _rb * 64 + lane) * 16),                \
          (__attribute__((address_space(3))) void*)(smB + (CUR) * (4 * 128 * 16) +       \
              (_u * 128 + _rb * 64 + lane) * 16),                                        \
          16, 0, 0);                                                                     \
    }                                                                                    \
  } while (0)

#define DO_STEP(ST, CUR) do {                                                            \
    const int _st = (ST);                                                                \
    /* buf[CUR] ready: only step _st+1's 6 loads may stay outstanding */                 \
    if (_st < TOTAL_STEPS - 1) asm volatile("s_waitcnt vmcnt(6)" ::: "memory");          \
    else                       asm volatile("s_waitcnt vmcnt(0)" ::: "memory");          \
    __builtin_amdgcn_sched_barrier(0);                                                   \
    __builtin_amdgcn_s_barrier();      /* publish buf[CUR] to all waves */               \
    union { intx8 v; uint4 q[2]; } a[2], b[4];                                           \
    {                                                                                    \
      const int ua = half * 2;                                                           \
      _Pragma("unroll")                                                                  \
      for (int mb = 0; mb < 2; ++mb) {                                                   \
        a[mb].q[0] = *(const uint4*)(smA + (CUR) * (4 * 256 * 16) +                      \
                                     ((ua * 256 + wr + mb * 32 + l31) * 16));            \
        a[mb].q[1] = *(const uint4*)(smA + (CUR) * (4 * 256 * 16) +                      \
                                     (((ua + 1) * 256 + wr + mb * 32 + l31) * 16));      \
      }                                                                                  \
      _Pragma("unroll")                                                                  \
      for (int nb = 0; nb < 4; ++nb) {                                                   \
        b[nb].q[0] = *(const uint4*)(smB + (CUR) * (4 * 128 * 16) +                      \
                                     ((ua * 128 + nb * 32 + l31) * 16));                 \
        b[nb].q[1] = *(const uint4*)(smB + (CUR) * (4 * 128 * 16) +                      \
                                     (((ua + 1) * 128 + nb * 32 + l31) * 16));           \
      }                                                                                  \
    }                                                                                    \
    asm volatile("s_waitcnt lgkmcnt(0)" ::: "memory");  /* my frag reads retired */      \
    __builtin_amdgcn_sched_barrier(0);                                                   \
    __builtin_amdgcn_s_barrier();      /* ALL waves done reading buf[CUR] */             \
    __builtin_amdgcn_sched_barrier(0);                                                   \
    if (_st + 2 < TOTAL_STEPS) STAGE(_st + 2, CUR);  /* overwrite is now safe */         \
    __builtin_amdgcn_sched_barrier(0);                                                   \
    __builtin_amdgcn_s_setprio(1);                                                       \
    _Pragma("unroll")                                                                    \
    for (int mb = 0; mb < 2; ++mb)                                                       \
      _Pragma("unroll")                                                                  \
      for (int nb = 0; nb < 4; ++nb)                                                     \
        acc[mb][nb] = __builtin_amdgcn_mfma_scale_f32_32x32x64_f8f6f4(                   \
            a[mb].v, b[nb].v, acc[mb][nb],                                               \
            0, 0,                      /* fp8 e4m3 A and B */                            \
            0, 0x7F7F7F7F,             /* scale A = 1.0 */                               \
            0, 0x7F7F7F7F);            /* scale B = 1.0 */                               \
    __builtin_amdgcn_s_setprio(0);                                                       \
  } while (0)

__global__ __launch_bounds__(256, 2) void flce_main(const unsigned char* __restrict__ xs,
                                                    const unsigned char* __restrict__ wsb,
                                                    const float* __restrict__ biasp,
                                                    float* __restrict__ partials) {
  __shared__ __align__(16) unsigned char smA[2 * 4 * 256 * 16];  // 32KB: dbuf A [u][row][16B]
  __shared__ __align__(16) unsigned char smB[2 * 4 * 128 * 16];  // 16KB: dbuf B
  __shared__ __align__(16) float sbias[TILES_PER_SPLIT * BN];    // 8KB: this split's bias slice

  const int tid  = threadIdx.x;
  const int lane = tid & 63;
  const int w    = tid >> 6;      // wave 0..3: rows [w*64, w*64+64)
  const int l31  = lane & 31;
  const int half = lane >> 5;     // k-half within MFMA (32 k each)
  const int wr   = w * 64;
  const int row0 = blockIdx.x * BM;
  const int sidx = blockIdx.y;

  float l_state[32];              // slot = mb*16 + reg; per-lane Σ 2^v over its cols
#pragma unroll
  for (int i = 0; i < 32; ++i) l_state[i] = 0.f;

  // Prologue: bias slice -> LDS (2 DMAs), then prefetch steps 0 and 1.
  // vmcnt retires in issue order, so the first vmcnt(6) also covers the bias DMAs.
#pragma unroll
  for (int j = 0; j < 2; ++j) {
    const int c = j * 4 + w;      // 8 chunks of 256 floats
    __builtin_amdgcn_global_load_lds(
        (const __attribute__((address_space(1))) void*)(biasp +
            (size_t)sidx * (TILES_PER_SPLIT * BN) + c * 256 + lane * 4),
        (__attribute__((address_space(3))) void*)(sbias + c * 256 + lane * 4),
        16, 0, 0);
  }
  STAGE(0, 0);
  STAGE(1, 1);

#pragma unroll 1
  for (int ct = 0; ct < TILES_PER_SPLIT; ++ct) {
    floatx16 acc[2][4];
#pragma unroll
    for (int mb = 0; mb < 2; ++mb)
#pragma unroll
      for (int nb = 0; nb < 4; ++nb)
#pragma unroll
        for (int i = 0; i < 16; ++i) acc[mb][nb][i] = 0.f;

#pragma unroll 1
    for (int ks2 = 0; ks2 < 8; ++ks2) {        // 16 K-steps, unrolled x2 so CUR is literal
      const int st0 = ct * 16 + ks2 * 2;       // ct*16 even -> parity of st == parity of ks
      DO_STEP(st0, 0);
      DO_STEP(st0 + 1, 1);
    }

    // Epilogue: Σ 2^(acc + bias2). Bias from LDS (lgkmcnt) -- keeps the loop's
    // vmcnt counting exact. C/D 32x32 layout [m74/m101]:
    // col = nb*32 + l31, row = wr + mb*32 + 4*half + (r&3) + 8*(r>>2).
    float bnb[4];
#pragma unroll
    for (int nb = 0; nb < 4; ++nb) bnb[nb] = sbias[ct * BN + nb * 32 + l31];
#pragma unroll
    for (int mb = 0; mb < 2; ++mb)
#pragma unroll
      for (int r = 0; r < 16; ++r) {
        float s = exp2f(acc[mb][0][r] + bnb[0]) + exp2f(acc[mb][1][r] + bnb[1])
                + exp2f(acc[mb][2][r] + bnb[2]) + exp2f(acc[mb][3][r] + bnb[3]);
        l_state[mb * 16 + r] += s;
      }
  }

  // Sum over this wave's 128 cols: butterfly within the 32-lane half (rows differ per half).
#pragma unroll
  for (int s = 0; s < 32; ++s) {
    float v = l_state[s];
#pragma unroll
    for (int off = 1; off < 32; off <<= 1) v += __shfl_xor(v, off, 64);
    l_state[s] = v;
  }

  // Each wave owns all cols of its 64 rows -> direct write, no cross-wave combine.
  if (l31 == 0) {
#pragma unroll
    for (int s = 0; s < 32; ++s) {
      const int mb = s >> 4, r = s & 15;
      const int row = wr + mb * 32 + 4 * half + (r & 3) + 8 * (r >> 2);
      partials[(size_t)(row0 + row) * S_SPLITS + sidx] = l_state[s];
    }
  }
}

// Exact fp32 target logit: one wave per row.
__global__ __launch_bounds__(256) void tgt_kernel(const float* __restrict__ x,
                                                  const float* __restrict__ wgt,
                                                  const float* __restrict__ bias,
                                                  const int* __restrict__ target,
                                                  float* __restrict__ tgt_logit) {
  const int r = blockIdx.x * 4 + (threadIdx.x >> 6);
  const int lane = threadIdx.x & 63;
  const int t = target[r];
  const int tt = (t == IGNORE_INDEX) ? 0 : t;
  const float4* xr = (const float4*)(x + (size_t)r * H_DIM);
  const float4* wr = (const float4*)(wgt + (size_t)tt * H_DIM);
  float acc = 0.f;
#pragma unroll
  for (int i = 0; i < 4; ++i) {
    const float4 a = xr[lane + i * 64];
    const float4 b = wr[lane + i * 64];
    acc += a.x * b.x + a.y * b.y + a.z * b.z + a.w * b.w;
  }
#pragma unroll
  for (int off = 32; off >= 1; off >>= 1) acc += __shfl_xor(acc, off, 64);
  if (lane == 0) tgt_logit[r] = acc + bias[tt];
}

// Per-row loss + per-block partial sums. partials hold Σ2^v per (row, split):
// lse_nat = ln2 * log2(Σ_s l_s).
__global__ __launch_bounds__(256) void loss_rows(const float* __restrict__ partials,
                                                 const float* __restrict__ tgt_logit,
                                                 const int* __restrict__ target,
                                                 float* __restrict__ bsums) {
  const int r = blockIdx.x * 256 + threadIdx.x;
  float l = 0.f;
#pragma unroll
  for (int s = 0; s < S_SPLITS; ++s) l += partials[(size_t)r * S_SPLITS + s];
  const float lse = LN2 * __log2f(l);
  const bool valid = (target[r] != IGNORE_INDEX);
  float loss = valid ? (lse - tgt_logit[r]) : 0.f;
  float cnt  = valid ? 1.f : 0.f;
  const int lane = threadIdx.x & 63;
  const int w = threadIdx.x >> 6;
#pragma unroll
  for (int off = 32; off >= 1; off >>= 1) {
    loss += __shfl_xor(loss, off, 64);
    cnt  += __shfl_xor(cnt, off, 64);
  }
  __shared__ float sl[4], sc[4];
  if (lane == 0) { sl[w] = loss; sc[w] = cnt; }
  __syncthreads();
  if (threadIdx.x == 0) {
    float S = 0.f, C = 0.f;
    for (int i = 0; i < 4; ++i) { S += sl[i]; C += sc[i]; }
    bsums[blockIdx.x] = S;
    bsums[32 + blockIdx.x] = C;
  }
}

__global__ void finalize(const float* __restrict__ bsums, float* __restrict__ out) {
  const int t = threadIdx.x;  // 64 threads
  float s = (t < 32) ? bsums[t] : 0.f;
  float c = (t < 32) ? bsums[32 + t] : 0.f;
#pragma unroll
  for (int off = 32; off >= 1; off >>= 1) {
    s += __shfl_xor(s, off, 64);
    c += __shfl_xor(c, off, 64);
  }
  if (t == 0) out[0] = s / fmaxf(c, 1.f);
}

extern "C" void kernel_launch(void* const* d_in, const int* in_sizes, int n_in,
                              void* d_out, int out_size, void* d_ws, size_t ws_size,
                              hipStream_t stream) {
  const float* x    = (const float*)d_in[0];
  const float* wgt  = (const float*)d_in[1];
  const float* bias = (const float*)d_in[2];
  const int*   tgt  = (const int*)d_in[3];
  float* out = (float*)d_out;

  char* ws = (char*)d_ws;
  const size_t XS8 = (size_t)N_ROWS * H_DIM;        // 8 MB fp8 x (pre-scaled by log2e)
  const size_t WS8 = (size_t)V_PAD * H_DIM;         // 33.5 MB fp8 W (rows >= V_DIM stay poisoned)
  const size_t BP  = (size_t)V_PAD * 4;             // padded bias (base-2 domain)
  const size_t PB  = (size_t)N_ROWS * S_SPLITS * 4; // per-(row,split) sumexp
  unsigned char* xs8 = (unsigned char*)ws;
  unsigned char* ws8 = (unsigned char*)(ws + XS8);
  float* biasp    = (float*)(ws + XS8 + WS8);
  float* partials = (float*)(ws + XS8 + WS8 + BP);
  float* tgt_lg   = (float*)(ws + XS8 + WS8 + BP + PB);
  float* bsums    = (float*)(ws + XS8 + WS8 + BP + PB + (size_t)N_ROWS * 4);

  convert_fp8<<<dim3(N_ROWS / 256, H_DIM / 16), 256, 0, stream>>>(x, xs8, N_ROWS, LOG2E);
  convert_fp8<<<dim3(V_DIM / 256, H_DIM / 16), 256, 0, stream>>>(wgt, ws8, V_PAD, 1.0f);
  pad_bias<<<V_PAD / 256, 256, 0, stream>>>(bias, biasp);
  tgt_kernel<<<N_ROWS / 4, 256, 0, stream>>>(x, wgt, bias, tgt, tgt_lg);
  flce_main<<<dim3(N_ROWS / BM, S_SPLITS), 256, 0, stream>>>(xs8, ws8, biasp, partials);
  loss_rows<<<N_ROWS / 256, 256, 0, stream>>>(partials, tgt_lg, tgt, bsums);
  finalize<<<1, 64, 0, stream>>>(bsums, out);
}

// Round 2
// 544.323 us; speedup vs baseline: 1.0069x; 1.0069x over previous
//
#include <hip/hip_runtime.h>
#include <math.h>

typedef int    intx8    __attribute__((ext_vector_type(8)));   // 8 dwords = 32 fp8
typedef float  floatx16 __attribute__((ext_vector_type(16)));  // MFMA 32x32 C/D

#define N_ROWS 8192
#define H_DIM  1024
#define V_DIM  32000
#define V_PAD  32768         // padded V: pad cols killed via bias = -1e30
#define IGNORE_INDEX (-100)

#define S_SPLITS 16          // 16 splits x 16 tiles x 128 cols = 32768
#define TILES_PER_SPLIT 16
#define BM 256
#define BN 128
#define BK 64                // 4 k-units of 16B; one K=64 MFMA step
#define KSTEPS 16            // H_DIM / BK
#define TOTAL_STEPS (TILES_PER_SPLIT * KSTEPS)   // 256

#define ABUF_SZ (4 * 256 * 16)   // 16 KB per A step-buffer
#define BBUF_SZ (4 * 128 * 16)   // 8 KB per B step-buffer

#define LOG2E 1.4426950408889634f
#define LN2   0.6931471805599453f

// fp32 [R][1024] row-major -> fp8 e4m3 (value*scale), "unit-transposed"
// [64 k-units][Rstride][16B]. One thread per (u, r): 64B contiguous read, 16B coalesced write.
__global__ __launch_bounds__(256) void convert_fp8(const float* __restrict__ in,
                                                   unsigned char* __restrict__ out,
                                                   int Rstride, float scale) {
  const int r = blockIdx.x * 256 + threadIdx.x;
  const int u = blockIdx.y;                  // k-unit 0..63
  const float4* src = (const float4*)(in + (size_t)r * H_DIM + u * 16);
  uint4 res;
#pragma unroll
  for (int j = 0; j < 4; ++j) {
    const float4 v = src[j];
    int p = __builtin_amdgcn_cvt_pk_fp8_f32(v.x * scale, v.y * scale, 0, false);
    p = __builtin_amdgcn_cvt_pk_fp8_f32(v.z * scale, v.w * scale, p, true);
    ((int*)&res)[j] = p;
  }
  *(uint4*)(out + ((size_t)u * Rstride + r) * 16) = res;
}

// Padded bias, pre-scaled to base-2 domain. Pad cols get -1e30 -> exp2 -> 0
// (poisoned pad weights give finite acc; -1e30 dominates).
__global__ __launch_bounds__(256) void pad_bias(const float* __restrict__ bias,
                                                float* __restrict__ biasp) {
  const int i = blockIdx.x * 256 + threadIdx.x;
  biasp[i] = (i < V_DIM) ? bias[i] * LOG2E : -1e30f;
}

// Fused GEMM + sumexp. fp8 e4m3, x pre-scaled by log2e (base-2 softmax domain).
// mfma_scale_f32_32x32x64_f8f6f4, unity scales (0x7F = E8M0 2^0).
//
// Round-2 schedule: 3-deep LDS buffers, ONE barrier per K-step, counted vmcnt.
//   step st: vmcnt(6) [retires STAGE(st)] -> s_barrier [publishes buf st to all
//   waves] -> STAGE(st+2) into buf[(st+2)%3] -> frag ds_reads from buf[st%3] ->
//   8 MFMA. Compiler manages lgkmcnt (frag reads are plain loads, no asm ds_read).
// WAR safety of 3-deep: buf[(st+2)%3] was last read at step st-1; every wave's
// st-1 reads retired before its st-1 MFMAs (compiler lgkmcnt), which are fenced
// above barrier(st) by sched_barrier(0). So post-barrier staging is race-free
// with NO second barrier -- this removes the long a/b live ranges that caused
// round-1's 199MB scratch-spill traffic.
// vmcnt discipline: steady-state outstanding = STAGE(st)+STAGE(st+1) = 12;
// vmcnt(6) waits exactly for STAGE(st). Prologue bias DMAs (2/wave) are oldest
// and retire inside step-0's vmcnt(6). No other vmem op exists in the loop.
// Grid 32x16 = 512 blocks = exactly 2/CU (80KB LDS x2 = 160KB): one clean
// residency round, no tail.

#define STAGE(ST, BUF) do {                                                              \
    const int _ss = (ST);                                                                \
    const int _ks = _ss & 15;                                                            \
    const int _ct = _ss >> 4;                                                            \
    const int _ub = _ks * 4;                                                             \
    const int _n0 = (sidx * TILES_PER_SPLIT + _ct) * BN;                                 \
    unsigned char* _dA = smA + (BUF) * ABUF_SZ;                                          \
    unsigned char* _dB = smB + (BUF) * BBUF_SZ;                                          \
    _Pragma("unroll")                                                                    \
    for (int _j = 0; _j < 4; ++_j) {                                                     \
      const int _c = _j * 4 + w, _u = _c >> 2, _rb = _c & 3;                             \
      __builtin_amdgcn_global_load_lds(                                                  \
          (const __attribute__((address_space(1))) void*)(xs +                           \
              ((size_t)(_ub + _u) * N_ROWS + row0 + _rb * 64 + lane) * 16),              \
          (__attribute__((address_space(3))) void*)(_dA + (_u * 256 + _rb * 64 + lane) * 16), \
          16, 0, 0);                                                                     \
    }                                                                                    \
    _Pragma("unroll")                                                                    \
    for (int _j = 0; _j < 2; ++_j) {                                                     \
      const int _c = _j * 4 + w, _u = _c >> 1, _rb = _c & 1;                             \
      __builtin_amdgcn_global_load_lds(                                                  \
          (const __attribute__((address_space(1))) void*)(wsb +                          \
              ((size_t)(_ub + _u) * V_PAD + _n0 + _rb * 64 + lane) * 16),                \
          (__attribute__((address_space(3))) void*)(_dB + (_u * 128 + _rb * 64 + lane) * 16), \
          16, 0, 0);                                                                     \
    }                                                                                    \
  } while (0)

__global__ __launch_bounds__(256, 2) void flce_main(const unsigned char* __restrict__ xs,
                                                    const unsigned char* __restrict__ wsb,
                                                    const float* __restrict__ biasp,
                                                    float* __restrict__ partials) {
  __shared__ __align__(16) unsigned char smA[3 * ABUF_SZ];      // 48KB: 3-deep A
  __shared__ __align__(16) unsigned char smB[3 * BBUF_SZ];      // 24KB: 3-deep B
  __shared__ __align__(16) float sbias[TILES_PER_SPLIT * BN];   // 8KB: split's bias slice

  const int tid  = threadIdx.x;
  const int lane = tid & 63;
  const int w    = tid >> 6;      // wave 0..3: rows [w*64, w*64+64)
  const int l31  = lane & 31;
  const int half = lane >> 5;     // k-half within MFMA (32 k each)
  const int wr   = w * 64;
  const int row0 = blockIdx.x * BM;
  const int sidx = blockIdx.y;

  float l_state[32];              // slot = mb*16 + reg; per-lane Σ 2^v over its cols
#pragma unroll
  for (int i = 0; i < 32; ++i) l_state[i] = 0.f;

  // Prologue: bias slice -> LDS (2 DMAs/wave), then prefetch steps 0 and 1.
  // vmcnt retires in issue order: step-0's vmcnt(6) covers bias + STAGE(0).
#pragma unroll
  for (int j = 0; j < 2; ++j) {
    const int c = j * 4 + w;      // 8 chunks of 256 floats
    __builtin_amdgcn_global_load_lds(
        (const __attribute__((address_space(1))) void*)(biasp +
            (size_t)sidx * (TILES_PER_SPLIT * BN) + c * 256 + lane * 4),
        (__attribute__((address_space(3))) void*)(sbias + c * 256 + lane * 4),
        16, 0, 0);
  }
  STAGE(0, 0);
  STAGE(1, 1);

  int b0 = 0, b1 = 1, b2 = 2;     // buffers of steps st, st+1, st+2 (rotate mod 3)

#pragma unroll 1
  for (int ct = 0; ct < TILES_PER_SPLIT; ++ct) {
    floatx16 acc[2][4];
#pragma unroll
    for (int mb = 0; mb < 2; ++mb)
#pragma unroll
      for (int nb = 0; nb < 4; ++nb)
#pragma unroll
        for (int i = 0; i < 16; ++i) acc[mb][nb][i] = 0.f;

#pragma unroll 1
    for (int ks = 0; ks < KSTEPS; ++ks) {
      const int st = ct * KSTEPS + ks;

      // buf[b0] ready: only STAGE(st+1) may stay outstanding (12 -> 6).
      if (st == TOTAL_STEPS - 1) asm volatile("s_waitcnt vmcnt(0)" ::: "memory");
      else                       asm volatile("s_waitcnt vmcnt(6)" ::: "memory");
      __builtin_amdgcn_sched_barrier(0);
      __builtin_amdgcn_s_barrier();       // publish buf[b0]; also proves all waves
      __builtin_amdgcn_sched_barrier(0);  // retired their step st-1 frag reads

      if (st + 2 < TOTAL_STEPS) STAGE(st + 2, b2);   // overwrite of step st-1's buf: safe

      // Fragment reads from buf[b0]; compiler inserts fine-grained lgkmcnt.
      union { intx8 v; uint4 q[2]; } a[2], b[4];
      const unsigned char* pA = smA + b0 * ABUF_SZ;
      const unsigned char* pB = smB + b0 * BBUF_SZ;
      const int ua = half * 2;            // this lane-half's 2 k-units
#pragma unroll
      for (int mb = 0; mb < 2; ++mb) {
        a[mb].q[0] = *(const uint4*)(pA + ((ua * 256 + wr + mb * 32 + l31) * 16));
        a[mb].q[1] = *(const uint4*)(pA + (((ua + 1) * 256 + wr + mb * 32 + l31) * 16));
      }
#pragma unroll
      for (int nb = 0; nb < 4; ++nb) {
        b[nb].q[0] = *(const uint4*)(pB + ((ua * 128 + nb * 32 + l31) * 16));
        b[nb].q[1] = *(const uint4*)(pB + (((ua + 1) * 128 + nb * 32 + l31) * 16));
      }

      __builtin_amdgcn_s_setprio(1);
#pragma unroll
      for (int mb = 0; mb < 2; ++mb)
#pragma unroll
        for (int nb = 0; nb < 4; ++nb)
          acc[mb][nb] = __builtin_amdgcn_mfma_scale_f32_32x32x64_f8f6f4(
              a[mb].v, b[nb].v, acc[mb][nb],
              0, 0,                      // fp8 e4m3 A and B
              0, 0x7F7F7F7F,             // scale A = 1.0
              0, 0x7F7F7F7F);            // scale B = 1.0
      __builtin_amdgcn_s_setprio(0);

      const int bt = b0; b0 = b1; b1 = b2; b2 = bt;   // rotate buffers
    }

    // Epilogue: Σ 2^(acc + bias2). Bias from LDS (lgkm-only -- keeps the loop's
    // vmcnt counting exact). C/D 32x32 layout [m74/m101]:
    // col = nb*32 + l31, row = wr + mb*32 + 4*half + (r&3) + 8*(r>>2).
    float bnb[4];
#pragma unroll
    for (int nb = 0; nb < 4; ++nb) bnb[nb] = sbias[ct * BN + nb * 32 + l31];
#pragma unroll
    for (int mb = 0; mb < 2; ++mb)
#pragma unroll
      for (int r = 0; r < 16; ++r) {
        float s = exp2f(acc[mb][0][r] + bnb[0]) + exp2f(acc[mb][1][r] + bnb[1])
                + exp2f(acc[mb][2][r] + bnb[2]) + exp2f(acc[mb][3][r] + bnb[3]);
        l_state[mb * 16 + r] += s;
      }
  }

  // Sum over this wave's 128 cols: butterfly within the 32-lane half (rows differ per half).
#pragma unroll
  for (int s = 0; s < 32; ++s) {
    float v = l_state[s];
#pragma unroll
    for (int off = 1; off < 32; off <<= 1) v += __shfl_xor(v, off, 64);
    l_state[s] = v;
  }

  // Each wave owns all cols of its 64 rows -> direct write, no cross-wave combine.
  if (l31 == 0) {
#pragma unroll
    for (int s = 0; s < 32; ++s) {
      const int mb = s >> 4, r = s & 15;
      const int row = wr + mb * 32 + 4 * half + (r & 3) + 8 * (r >> 2);
      partials[(size_t)(row0 + row) * S_SPLITS + sidx] = l_state[s];
    }
  }
}

// Exact fp32 target logit: one wave per row.
__global__ __launch_bounds__(256) void tgt_kernel(const float* __restrict__ x,
                                                  const float* __restrict__ wgt,
                                                  const float* __restrict__ bias,
                                                  const int* __restrict__ target,
                                                  float* __restrict__ tgt_logit) {
  const int r = blockIdx.x * 4 + (threadIdx.x >> 6);
  const int lane = threadIdx.x & 63;
  const int t = target[r];
  const int tt = (t == IGNORE_INDEX) ? 0 : t;
  const float4* xr = (const float4*)(x + (size_t)r * H_DIM);
  const float4* wr = (const float4*)(wgt + (size_t)tt * H_DIM);
  float acc = 0.f;
#pragma unroll
  for (int i = 0; i < 4; ++i) {
    const float4 a = xr[lane + i * 64];
    const float4 b = wr[lane + i * 64];
    acc += a.x * b.x + a.y * b.y + a.z * b.z + a.w * b.w;
  }
#pragma unroll
  for (int off = 32; off >= 1; off >>= 1) acc += __shfl_xor(acc, off, 64);
  if (lane == 0) tgt_logit[r] = acc + bias[tt];
}

// Per-row loss + per-block partial sums. partials hold Σ2^v per (row, split):
// lse_nat = ln2 * log2(Σ_s l_s).
__global__ __launch_bounds__(256) void loss_rows(const float* __restrict__ partials,
                                                 const float* __restrict__ tgt_logit,
                                                 const int* __restrict__ target,
                                                 float* __restrict__ bsums) {
  const int r = blockIdx.x * 256 + threadIdx.x;
  float l = 0.f;
#pragma unroll
  for (int s = 0; s < S_SPLITS; ++s) l += partials[(size_t)r * S_SPLITS + s];
  const float lse = LN2 * __log2f(l);
  const bool valid = (target[r] != IGNORE_INDEX);
  float loss = valid ? (lse - tgt_logit[r]) : 0.f;
  float cnt  = valid ? 1.f : 0.f;
  const int lane = threadIdx.x & 63;
  const int w = threadIdx.x >> 6;
#pragma unroll
  for (int off = 32; off >= 1; off >>= 1) {
    loss += __shfl_xor(loss, off, 64);
    cnt  += __shfl_xor(cnt, off, 64);
  }
  __shared__ float sl[4], sc[4];
  if (lane == 0) { sl[w] = loss; sc[w] = cnt; }
  __syncthreads();
  if (threadIdx.x == 0) {
    float S = 0.f, C = 0.f;
    for (int i = 0; i < 4; ++i) { S += sl[i]; C += sc[i]; }
    bsums[blockIdx.x] = S;
    bsums[32 + blockIdx.x] = C;
  }
}

__global__ void finalize(const float* __restrict__ bsums, float* __restrict__ out) {
  const int t = threadIdx.x;  // 64 threads
  float s = (t < 32) ? bsums[t] : 0.f;
  float c = (t < 32) ? bsums[32 + t] : 0.f;
#pragma unroll
  for (int off = 32; off >= 1; off >>= 1) {
    s += __shfl_xor(s, off, 64);
    c += __shfl_xor(c, off, 64);
  }
  if (t == 0) out[0] = s / fmaxf(c, 1.f);
}

extern "C" void kernel_launch(void* const* d_in, const int* in_sizes, int n_in,
                              void* d_out, int out_size, void* d_ws, size_t ws_size,
                              hipStream_t stream) {
  const float* x    = (const float*)d_in[0];
  const float* wgt  = (const float*)d_in[1];
  const float* bias = (const float*)d_in[2];
  const int*   tgt  = (const int*)d_in[3];
  float* out = (float*)d_out;

  char* ws = (char*)d_ws;
  const size_t XS8 = (size_t)N_ROWS * H_DIM;        // 8 MB fp8 x (pre-scaled by log2e)
  const size_t WS8 = (size_t)V_PAD * H_DIM;         // 33.5 MB fp8 W (rows >= V_DIM stay poisoned)
  const size_t BP  = (size_t)V_PAD * 4;             // padded bias (base-2 domain)
  const size_t PB  = (size_t)N_ROWS * S_SPLITS * 4; // per-(row,split) sumexp
  unsigned char* xs8 = (unsigned char*)ws;
  unsigned char* ws8 = (unsigned char*)(ws + XS8);
  float* biasp    = (float*)(ws + XS8 + WS8);
  float* partials = (float*)(ws + XS8 + WS8 + BP);
  float* tgt_lg   = (float*)(ws + XS8 + WS8 + BP + PB);
  float* bsums    = (float*)(ws + XS8 + WS8 + BP + PB + (size_t)N_ROWS * 4);

  convert_fp8<<<dim3(N_ROWS / 256, H_DIM / 16), 256, 0, stream>>>(x, xs8, N_ROWS, LOG2E);
  convert_fp8<<<dim3(V_DIM / 256, H_DIM / 16), 256, 0, stream>>>(wgt, ws8, V_PAD, 1.0f);
  pad_bias<<<V_PAD / 256, 256, 0, stream>>>(bias, biasp);
  tgt_kernel<<<N_ROWS / 4, 256, 0, stream>>>(x, wgt, bias, tgt, tgt_lg);
  flce_main<<<dim3(N_ROWS / BM, S_SPLITS), 256, 0, stream>>>(xs8, ws8, biasp, partials);
  loss_rows<<<N_ROWS / 256, 256, 0, stream>>>(partials, tgt_lg, tgt, bsums);
  finalize<<<1, 64, 0, stream>>>(bsums, out);
}